// Round 13
// baseline (291.796 us; speedup 1.0000x reference)
//
#include <hip/hip_runtime.h>

// RepformerLayer attention: nf=1, nloc=1024, nnei=128, ng2=nd=32, nh=4. f32 I/O.
// Transposed dataflow, K32-only (r2 math): q2^T C-layout feeds S^T MFMAs via
// PERMUTED NQ rows; permuted G2T rows make T^T C-tiles concat into the og
// A-frag; S^T A-rows read permuted so lane-local P rows land in value-MFMA
// B-frag k-slots. Lane holds a full softmax ROW (2-shuffle denom); P/T never
// touch LDS. hd loop ROLLED (r5); native cvt_pk (r6); packed-f32 softmax +
// per-wave head rotation (r11); PQ loads hoisted (r12); 512-thr blocks, one
// strip/wave, fold pre-kernel -> ws, 4 blocks/CU = 8 waves/SIMD (r9).
// THIS ROUND: (1) fold pre-kernel parallelized to 8 blocks x 64 thr (was 1
// block latency-bound on one CU; work partitions disjointly by (h,mt)) —
// cuts serial wall time ahead of the main kernel. (2) end-of-head FENCE
// removed: rolled loop's backedge bounds live ranges (r4's spill was from
// FULL unroll, not fence absence); lets LLVM software-pipeline next head's
// NQ/PQ L2 loads under current head's exp/value chain. Spill tripwire:
// WRITE_SIZE (~21 MB expected; >30 MB => reverted next round).

typedef __bf16 v8bf __attribute__((ext_vector_type(8)));
typedef float  v4f  __attribute__((ext_vector_type(4)));
typedef float  f2   __attribute__((ext_vector_type(2)));
typedef unsigned u32x2 __attribute__((ext_vector_type(2)));
typedef unsigned u32x4 __attribute__((ext_vector_type(4)));

__device__ __forceinline__ float b2f(unsigned short b) {
    union { unsigned u; float f; } x; x.u = ((unsigned)b) << 16; return x.f;
}
__device__ __forceinline__ unsigned short fb(float f) {      // RNE f32->bf16
    return __builtin_bit_cast(unsigned short, (__bf16)f);
}
struct HL { unsigned short hi, lo; };
__device__ __forceinline__ HL splitbf(float f) {
    HL r; r.hi = fb(f); r.lo = fb(f - b2f(r.hi)); return r;
}
__device__ __forceinline__ unsigned pk2(unsigned short lo, unsigned short hi) {
    return ((unsigned)hi << 16) | (unsigned)lo;
}
__device__ __forceinline__ unsigned cvt2(float a, float b) { // lo=a hi=b
    return pk2(fb(a), fb(b));
}
__device__ __forceinline__ void sp2(float a, float b, unsigned& hi, unsigned& lo) {
    __bf16 ah = (__bf16)a, bh = (__bf16)b;
    hi = pk2(__builtin_bit_cast(unsigned short, ah), __builtin_bit_cast(unsigned short, bh));
    lo = cvt2(a - (float)ah, b - (float)bh);
}
__device__ __forceinline__ v8bf mkv8(unsigned a, unsigned b, unsigned c, unsigned d) {
    u32x4 x = {a, b, c, d};
    return __builtin_bit_cast(v8bf, x);
}
__device__ __forceinline__ f2 mkf2(float a, float b) {
    f2 r; r[0] = a; r[1] = b; return r;
}
__device__ __forceinline__ float hwe(const float* h2s, int kn,
                                     float hq0, float hq1, float hq2) {
    const v4f hk = *(const v4f*)(h2s + kn * 4);
    return fmaf(hq2, hk[2], fmaf(hq1, hk[1], hq0 * hk[0]));
}

#define MF(a,b,c) __builtin_amdgcn_mfma_f32_16x16x32_bf16((a),(b),(c),0,0,0)
#define FENCE() asm volatile("" ::: "memory")
#define FMA2(a,b,c) __builtin_elementwise_fma((a),(b),(c))

#if __has_builtin(__builtin_amdgcn_exp2f)
#define EXP2(x) __builtin_amdgcn_exp2f(x)
#else
#define EXP2(x) __expf((x) * 0.6931471805599453f)
#endif

#define MSH (-28.853900817779268f)

// ws offsets (u16 units): NQH 0 | NQL 4096 | PQ 8192  (24576 B total)
#define NQHo 0
#define NQLo 4096
#define PQo  8192

// LDS offsets (u16 units), main kernel
#define G2H 0        // [128][32] g2 hi, col ^= KEY(row)
#define G2L 4096     // [128][32] g2 lo, same swizzle
#define G2T 8192     // [32][136] g2^T * es[k], rows PERMUTED, hi only
#define H2T 12544    // [4][136] h2^T * es[k], row 3 zeros
#define SM_U16 13088 // 26176 B + 3088 smf = 29264 B -> 4 blocks/CU (wave cap)

#define RPERM(C) ((((C) >> 2) & 1) * 16 + (((C) >> 3) << 2) + ((C) & 3))
#define KEY(R) ((((R) & 3) ^ (((R) >> 3) & 3)) << 3)

#define CC_(a,b) a##b
#define CC(a,b) CC_(a,b)

// declare 8 named HL splits; IDX must be a function-like macro
#define LD8(NM, IDX) \
    HL CC(NM,0) = splitbf(IDX(0)), CC(NM,1) = splitbf(IDX(1)), \
       CC(NM,2) = splitbf(IDX(2)), CC(NM,3) = splitbf(IDX(3)), \
       CC(NM,4) = splitbf(IDX(4)), CC(NM,5) = splitbf(IDX(5)), \
       CC(NM,6) = splitbf(IDX(6)), CC(NM,7) = splitbf(IDX(7));
#define HI8(NM) mkv8(pk2(CC(NM,0).hi, CC(NM,1).hi), pk2(CC(NM,2).hi, CC(NM,3).hi), \
                     pk2(CC(NM,4).hi, CC(NM,5).hi), pk2(CC(NM,6).hi, CC(NM,7).hi))
#define LO8(NM) mkv8(pk2(CC(NM,0).lo, CC(NM,1).lo), pk2(CC(NM,2).lo, CC(NM,3).lo), \
                     pk2(CC(NM,4).lo, CC(NM,5).lo), pk2(CC(NM,6).lo, CC(NM,7).lo))

#define WKI(J) wqk[(mt * 16 + n16) * 256 + (quad * 8 + (J)) * 8 + 4 + h]
#define WVI(J) wv[(mt * 16 + n16) * 128 + (quad * 8 + (J)) * 4 + h]
#define WQI(J) wqk[(nt * 16 + n16) * 256 + (quad * 8 + (J)) * 8 + h]
#define WHI(J) wh[((quad * 8 + (J)) * 4 + h) * 32 + nt * 16 + n16]

// ======= pre-kernel: fold weights once into ws (8 blocks x 64 thr) =========
__global__ __launch_bounds__(64) void fold_kernel(
    const float* __restrict__ wqk, const float* __restrict__ wv,
    const float* __restrict__ wh, unsigned short* __restrict__ wsu)
{
    const int lane = threadIdx.x;              // 0..63
    const int quad = lane >> 4;
    const int n16  = lane & 15;
    const int h    = blockIdx.x & 3;           // head
    const int mt   = blockIdx.x >> 2;          // row-block

    LD8(ak, WKI)                               // Wk[c][d] splits
    LD8(av, WVI)                               // Wv[c][g] splits
    const v8bf akh = HI8(ak), akl = LO8(ak);
    const v8bf avh = HI8(av), avl = LO8(av);
    FENCE();
    #pragma unroll 1
    for (int nt = 0; nt < 2; nt++) {
        LD8(bq, WQI)                           // Wq[c'][d] splits
        LD8(bw, WHI)                           // Wh[g][o] splits
        const v8bf bqh = HI8(bq), bql = LO8(bq);
        const v8bf bhh = HI8(bw), bhl = LO8(bw);
        FENCE();
        const v4f z = {0.f, 0.f, 0.f, 0.f};
        // c1[r] = M[nt*16+n16][x], x = mt*16+quad*4+r  (M = Wq Wk^T)
        v4f c1 = MF(akh, bqh, MF(akl, bqh, MF(akh, bql, z)));
        #pragma unroll
        for (int r = 0; r < 4; r++) {
            HL s1 = splitbf(c1[r]);
            int x    = mt * 16 + quad * 4 + r;
            int rowp = RPERM(x);
            int addr = h * 1024 + rowp * 32 + ((nt * 16 + n16) ^ KEY(rowp));
            wsu[NQHo + addr] = s1.hi; wsu[NQLo + addr] = s1.lo;
        }
        // c2[r] = W2fold[c = mt*16+quad*4+r][o = nt*16+n16]
        v4f c2 = MF(avh, bhh, MF(avl, bhh, MF(avh, bhl, z)));
        #pragma unroll
        for (int r = 0; r < 4; r++) {
            int o  = nt * 16 + n16;
            int cw = mt * 16 + quad * 4 + r;
            wsu[PQo + h * 1024 + o * 32 + (cw ^ KEY(o))] = fb(c2[r]);
        }
        FENCE();
    }
}

// ============================ main kernel ====================================
__global__ __launch_bounds__(512, 4) void repformer_kernel(
    const float* __restrict__ g2, const float* __restrict__ h2,
    const float* __restrict__ sw, const float* __restrict__ bh,
    const float* __restrict__ weq, const int* __restrict__ nmask,
    const unsigned short* __restrict__ wsu, float* __restrict__ out)
{
    __shared__ __align__(16) unsigned short sm[SM_U16];
    __shared__ __align__(16) float smf[772];   // h2s[512] | sws[128] | es[128] | weq[4]
    float* h2s = smf;
    float* sws = smf + 512;
    float* es  = smf + 640;
    float* wqs = smf + 768;

    const int t    = threadIdx.x;              // 0..511
    const int i    = blockIdx.x;
    const int lane = t & 63;
    const int w8   = t >> 6;                   // wave 0..7
    const int quad = lane >> 4;
    const int n16  = lane & 15;

    // ------- stage per-loc inputs (es folded inline into G2T/H2T) -------
    {
        const float4* src = (const float4*)(g2 + (size_t)i * 4096);
        #pragma unroll
        for (int j = 0; j < 2; j++) {
            int idx = j * 512 + t;
            float4 v = src[idx];
            HL a0 = splitbf(v.x), a1 = splitbf(v.y), a2 = splitbf(v.z), a3 = splitbf(v.w);
            int k = idx >> 3, c0 = (idx & 7) * 4;
            int swz = k * 32 + (c0 ^ KEY(k));
            *(u32x2*)(sm + G2H + swz) = (u32x2){pk2(a0.hi, a1.hi), pk2(a2.hi, a3.hi)};
            *(u32x2*)(sm + G2L + swz) = (u32x2){pk2(a0.lo, a1.lo), pk2(a2.lo, a3.lo)};
            float ek = (nmask[i * 128 + k] != 0) ? sw[i * 128 + k] : 0.0f;
            sm[G2T + RPERM(c0 + 0) * 136 + k] = fb(b2f(a0.hi) * ek);
            sm[G2T + RPERM(c0 + 1) * 136 + k] = fb(b2f(a1.hi) * ek);
            sm[G2T + RPERM(c0 + 2) * 136 + k] = fb(b2f(a2.hi) * ek);
            sm[G2T + RPERM(c0 + 3) * 136 + k] = fb(b2f(a3.hi) * ek);
        }
    }
    if (t < 384) {
        float f = h2[(size_t)i * 384 + t];
        int k = t / 3, c = t - k * 3;
        h2s[k * 4 + c] = f;
        float ek = (nmask[i * 128 + k] != 0) ? sw[i * 128 + k] : 0.0f;
        unsigned short us = fb(f);
        sm[H2T + c * 136 + k] = fb(b2f(us) * ek);
    }
    if (t < 128) {
        sm[H2T + 3 * 136 + t] = 0;
        float s = sw[i * 128 + t];
        sws[t] = s;
        es[t]  = (nmask[i * 128 + t] != 0) ? s : 0.0f;
    }
    if (t < 4) wqs[t] = weq[t];
    __syncthreads();   // all LDS is READ-ONLY from here to the end

    const int hr = (n16 < 3) ? n16 : 3;
    float* outg = out;
    float* outh = out + 4194304;   // 1024*128*32
    const float bias0 = bh[n16];
    const float bias1 = bh[16 + n16];
    // swizzled col bases (per-lane constants):
    const int qo0 = (quad * 8) ^ KEY(n16);               // NQ/PQ tile0 (row n16)
    const int qo1 = (quad * 8) ^ KEY(16 + n16);          // NQ/PQ tile1 (row 16+n16)
    const int rowbase = ((n16 >> 2) << 3) + (n16 & 3);   // S^T A-row permutation
    const int qoK = (quad * 8) ^ KEY(rowbase);           // KSSTEP A-rows
    const unsigned short* g2t0 = sm + G2T + n16 * 136;
    const unsigned short* g2t1 = sm + G2T + (16 + n16) * 136;
    const unsigned short* h2tp = sm + H2T + hr * 136;

// one 32-kn chunk: 2 S^T tiles -> packed-f32 softmax -> P-frag -> 3 value MFMAs
#define KSSTEP(KS, HWA, HWB) { \
    const int rowA = (KS) * 32 + rowbase; \
    const v8bf ah0 = *(const v8bf*)(sm + G2H + rowA * 32 + qoK); \
    const v8bf al0 = *(const v8bf*)(sm + G2L + rowA * 32 + qoK); \
    const v8bf ah1 = *(const v8bf*)(sm + G2H + (rowA + 4) * 32 + qoK); \
    const v8bf al1 = *(const v8bf*)(sm + G2L + (rowA + 4) * 32 + qoK); \
    const v4f st0 = MF(ah0, ql, MF(al0, qh, MF(ah0, qh, vz))); \
    const v4f st1 = MF(ah1, ql, MF(al1, qh, MF(ah1, qh, vz))); \
    const v4f swkA = *(const v4f*)(sws + (KS) * 32 + quad * 8); \
    const v4f swkB = *(const v4f*)(sws + (KS) * 32 + quad * 8 + 4); \
    const f2 l01 = FMA2(FMA2(mkf2(st0[0], st0[1]), mkf2((HWA)[0], (HWA)[1]), sq2v), \
                        mkf2(swkA[0], swkA[1]), mshv); \
    const f2 l23 = FMA2(FMA2(mkf2(st0[2], st0[3]), mkf2((HWA)[2], (HWA)[3]), sq2v), \
                        mkf2(swkA[2], swkA[3]), mshv); \
    const f2 l45 = FMA2(FMA2(mkf2(st1[0], st1[1]), mkf2((HWB)[0], (HWB)[1]), sq2v), \
                        mkf2(swkB[0], swkB[1]), mshv); \
    const f2 l67 = FMA2(FMA2(mkf2(st1[2], st1[3]), mkf2((HWB)[2], (HWB)[3]), sq2v), \
                        mkf2(swkB[2], swkB[3]), mshv); \
    const f2 p01 = mkf2(EXP2(l01[0]), EXP2(l01[1])); \
    const f2 p23 = mkf2(EXP2(l23[0]), EXP2(l23[1])); \
    const f2 p45 = mkf2(EXP2(l45[0]), EXP2(l45[1])); \
    const f2 p67 = mkf2(EXP2(l67[0]), EXP2(l67[1])); \
    sum2 += (p01 + p23) + (p45 + p67); \
    const f2 h01 = p01 * mkf2((HWA)[0], (HWA)[1]); \
    const f2 h23 = p23 * mkf2((HWA)[2], (HWA)[3]); \
    const f2 h45 = p45 * mkf2((HWB)[0], (HWB)[1]); \
    const f2 h67 = p67 * mkf2((HWB)[2], (HWB)[3]); \
    const v8bf pv = mkv8(cvt2(h01[0], h01[1]), cvt2(h23[0], h23[1]), \
                         cvt2(h45[0], h45[1]), cvt2(h67[0], h67[1])); \
    T0  = MF(*(const v8bf*)(g2t0 + (KS) * 32 + quad * 8), pv, T0); \
    T1  = MF(*(const v8bf*)(g2t1 + (KS) * 32 + quad * 8), pv, T1); \
    ohl = MF(*(const v8bf*)(h2tp + (KS) * 32 + quad * 8), pv, ohl); \
}

    // ============ ONE strip per wave (8 waves), heads INNER (rolled) ========
    {
        const int s = w8;
        const int q = s * 16 + n16;                      // this lane's q-row
        const int qoq = (quad * 8) ^ KEY(q);
        const v8bf gfh = *(const v8bf*)(sm + G2H + q * 32 + qoq);
        const v8bf gfl = *(const v8bf*)(sm + G2L + q * 32 + qoq);
        const float swq    = sws[q];
        const float mq     = (es[q] != 0.0f) ? 1.0f : 0.0f;
        const float swq20E = swq * 28.853900817779268f;  // 20*swq*log2e
        const f2 sq2v = mkf2(swq20E, swq20E);
        const f2 mshv = mkf2(MSH, MSH);
        const float kq     = 0.17677669529663687f * 1.4426950408889634f * swq;
        const float hq0 = h2s[q * 4 + 0] * kq;
        const float hq1 = h2s[q * 4 + 1] * kq;
        const float hq2 = h2s[q * 4 + 2] * kq;
        // htcwE = ht*swq/sqrt(32)*log2e, 8 named v4f (no arrays)
#define HW4(T8) (v4f){ hwe(h2s, ((T8) >> 1) * 32 + quad * 8 + ((T8) & 1) * 4 + 0, hq0, hq1, hq2), \
                       hwe(h2s, ((T8) >> 1) * 32 + quad * 8 + ((T8) & 1) * 4 + 1, hq0, hq1, hq2), \
                       hwe(h2s, ((T8) >> 1) * 32 + quad * 8 + ((T8) & 1) * 4 + 2, hq0, hq1, hq2), \
                       hwe(h2s, ((T8) >> 1) * 32 + quad * 8 + ((T8) & 1) * 4 + 3, hq0, hq1, hq2) }
        const v4f hw0 = HW4(0), hw1 = HW4(1), hw2 = HW4(2), hw3 = HW4(3);
        const v4f hw4 = HW4(4), hw5 = HW4(5), hw6 = HW4(6), hw7 = HW4(7);
        v4f og0 = {0.f, 0.f, 0.f, 0.f}, og1 = og0, ohacc = og0;
        FENCE();

        #pragma unroll 1
        for (int h0 = 0; h0 < 4; h0++) {
            const int hd = (h0 + w8) & 3;                // per-wave head rotation
            const v4f vz = {0.f, 0.f, 0.f, 0.f};
            // ---- q2^T: 2 C-tiles; NQ frags from GLOBAL ws (L2-hot) ----
            const unsigned short* nqh = wsu + NQHo + hd * 1024;
            const unsigned short* nql = wsu + NQLo + hd * 1024;
            const v8bf nh0 = *(const v8bf*)(nqh + n16 * 32 + qo0);
            const v8bf nl0 = *(const v8bf*)(nql + n16 * 32 + qo0);
            const v8bf nh1 = *(const v8bf*)(nqh + (16 + n16) * 32 + qo1);
            const v8bf nl1 = *(const v8bf*)(nql + (16 + n16) * 32 + qo1);
            // ---- PQ frags hoisted here: L2 latency hides under the softmax
            const unsigned short* wp = wsu + PQo + hd * 1024;
            const v8bf w0f = *(const v8bf*)(wp + n16 * 32 + qo0);
            const v8bf w1f = *(const v8bf*)(wp + (16 + n16) * 32 + qo1);
            v4f c0t = MF(nh0, gfl, MF(nl0, gfh, MF(nh0, gfh, vz)));
            v4f c1t = MF(nh1, gfl, MF(nl1, gfh, MF(nh1, gfh, vz)));
            unsigned qh0, qh1, qh2, qh3, ql0, ql1, ql2, ql3;
            sp2(c0t[0], c0t[1], qh0, ql0);
            sp2(c0t[2], c0t[3], qh1, ql1);
            sp2(c1t[0], c1t[1], qh2, ql2);
            sp2(c1t[2], c1t[3], qh3, ql3);
            const v8bf qh = mkv8(qh0, qh1, qh2, qh3);
            const v8bf ql = mkv8(ql0, ql1, ql2, ql3);
            // ---- 4 x 32-kn chunks (no fences: backedge bounds live ranges)
            v4f T0 = vz, T1 = vz, ohl = vz;
            f2 sum2 = mkf2(0.f, 0.f);
            KSSTEP(0, hw0, hw1)
            KSSTEP(1, hw2, hw3)
            KSSTEP(2, hw4, hw5)
            KSSTEP(3, hw6, hw7)
            float sum = sum2[0] + sum2[1];
            sum += __shfl_xor(sum, 16, 64);
            sum += __shfl_xor(sum, 32, 64);
            // mq * sqrt(32)/sqrt(3) * ln2 / denom  (ln2 un-does log2e in htcwE)
            const float scale = mq * 2.2638092f * __builtin_amdgcn_rcpf(sum);
            const f2 sc2 = mkf2(scale, scale);
            const f2 t01 = sc2 * mkf2(T0[0], T0[1]);
            const f2 t23 = sc2 * mkf2(T0[2], T0[3]);
            const f2 t45 = sc2 * mkf2(T1[0], T1[1]);
            const f2 t67 = sc2 * mkf2(T1[2], T1[3]);
            const v8bf ta = mkv8(cvt2(t01[0], t01[1]), cvt2(t23[0], t23[1]),
                                 cvt2(t45[0], t45[1]), cvt2(t67[0], t67[1]));
            og0 = MF(ta, w0f, og0);
            og1 = MF(ta, w1f, og1);
            const float ws = wqs[hd] * scale;
            ohacc[0] = fmaf(ws, ohl[0], ohacc[0]);
            ohacc[1] = fmaf(ws, ohl[1], ohacc[1]);
            ohacc[2] = fmaf(ws, ohl[2], ohacc[2]);
            ohacc[3] = fmaf(ws, ohl[3], ohacc[3]);
        }

        // ---- strip epilogue (f32 out): og rows = q (quad*4+r), cols = o ----
        const int qg = i * 128 + s * 16;
        #pragma unroll
        for (int r = 0; r < 4; r++) {
            outg[(size_t)(qg + quad * 4 + r) * 32 + n16]      = og0[r] + bias0;
            outg[(size_t)(qg + quad * 4 + r) * 32 + 16 + n16] = og1[r] + bias1;
        }
        if (quad == 0) {
            #pragma unroll
            for (int r = 0; r < 3; r++)
                outh[(size_t)(qg + n16) * 3 + r] = ohacc[r];
        }
    }
}

extern "C" void kernel_launch(void* const* d_in, const int* in_sizes, int n_in,
                              void* d_out, int out_size, void* d_ws, size_t ws_size,
                              hipStream_t stream) {
    const float* g2  = (const float*)d_in[0];
    const float* h2  = (const float*)d_in[1];
    const float* sw  = (const float*)d_in[2];
    const float* wqk = (const float*)d_in[3];
    const float* wv  = (const float*)d_in[4];
    const float* wh  = (const float*)d_in[5];
    const float* bh  = (const float*)d_in[6];
    const float* weq = (const float*)d_in[7];
    const int*   nm  = (const int*)d_in[8];
    unsigned short* wsu = (unsigned short*)d_ws;       // needs 24576 B
    int nloc = in_sizes[0] / (128 * 32);   // 1024
    fold_kernel<<<8, 64, 0, stream>>>(wqk, wv, wh, wsu);
    repformer_kernel<<<nloc, 512, 0, stream>>>(g2, h2, sw, bh, weq, nm, wsu, (float*)d_out);
}

// Round 14
// 120.169 us; speedup vs baseline: 2.4282x; 2.4282x over previous
//
#include <hip/hip_runtime.h>

// RepformerLayer attention: nf=1, nloc=1024, nnei=128, ng2=nd=32, nh=4. f32 I/O.
// Transposed dataflow, K32-only (r2 math): q2^T C-layout feeds S^T MFMAs via
// PERMUTED NQ rows; permuted G2T rows make T^T C-tiles concat into the og
// A-frag; S^T A-rows read permuted so lane-local P rows land in value-MFMA
// B-frag k-slots. Lane holds a full softmax ROW (2-shuffle denom); P/T never
// touch LDS. hd loop ROLLED + ONE end-of-head FENCE (r5/r13: the fence is the
// load-bearing barrier — without it LLVM pipelines across the backedge and
// spills at the 64-VGPR cap; r13 measured 568/306 MB scratch traffic).
// Native cvt_pk (r6); packed-f32 softmax + head rotation (r11); PQ loads
// hoisted, no mid-head fence (r12); 512-thr blocks, one strip/wave,
// 4 blocks/CU = 8 waves/SIMD (r9). Fold pre-kernel 8 blocks x 64 thr (r13's
// one safe piece). THIS ROUND: strict revert to r12 main kernel (best:
// 45.8 us rocprof) + parallel fold.

typedef __bf16 v8bf __attribute__((ext_vector_type(8)));
typedef float  v4f  __attribute__((ext_vector_type(4)));
typedef float  f2   __attribute__((ext_vector_type(2)));
typedef unsigned u32x2 __attribute__((ext_vector_type(2)));
typedef unsigned u32x4 __attribute__((ext_vector_type(4)));

__device__ __forceinline__ float b2f(unsigned short b) {
    union { unsigned u; float f; } x; x.u = ((unsigned)b) << 16; return x.f;
}
__device__ __forceinline__ unsigned short fb(float f) {      // RNE f32->bf16
    return __builtin_bit_cast(unsigned short, (__bf16)f);
}
struct HL { unsigned short hi, lo; };
__device__ __forceinline__ HL splitbf(float f) {
    HL r; r.hi = fb(f); r.lo = fb(f - b2f(r.hi)); return r;
}
__device__ __forceinline__ unsigned pk2(unsigned short lo, unsigned short hi) {
    return ((unsigned)hi << 16) | (unsigned)lo;
}
__device__ __forceinline__ unsigned cvt2(float a, float b) { // lo=a hi=b
    return pk2(fb(a), fb(b));
}
__device__ __forceinline__ void sp2(float a, float b, unsigned& hi, unsigned& lo) {
    __bf16 ah = (__bf16)a, bh = (__bf16)b;
    hi = pk2(__builtin_bit_cast(unsigned short, ah), __builtin_bit_cast(unsigned short, bh));
    lo = cvt2(a - (float)ah, b - (float)bh);
}
__device__ __forceinline__ v8bf mkv8(unsigned a, unsigned b, unsigned c, unsigned d) {
    u32x4 x = {a, b, c, d};
    return __builtin_bit_cast(v8bf, x);
}
__device__ __forceinline__ f2 mkf2(float a, float b) {
    f2 r; r[0] = a; r[1] = b; return r;
}
__device__ __forceinline__ float hwe(const float* h2s, int kn,
                                     float hq0, float hq1, float hq2) {
    const v4f hk = *(const v4f*)(h2s + kn * 4);
    return fmaf(hq2, hk[2], fmaf(hq1, hk[1], hq0 * hk[0]));
}

#define MF(a,b,c) __builtin_amdgcn_mfma_f32_16x16x32_bf16((a),(b),(c),0,0,0)
#define FENCE() asm volatile("" ::: "memory")
#define FMA2(a,b,c) __builtin_elementwise_fma((a),(b),(c))

#if __has_builtin(__builtin_amdgcn_exp2f)
#define EXP2(x) __builtin_amdgcn_exp2f(x)
#else
#define EXP2(x) __expf((x) * 0.6931471805599453f)
#endif

#define MSH (-28.853900817779268f)

// ws offsets (u16 units): NQH 0 | NQL 4096 | PQ 8192  (24576 B total)
#define NQHo 0
#define NQLo 4096
#define PQo  8192

// LDS offsets (u16 units), main kernel
#define G2H 0        // [128][32] g2 hi, col ^= KEY(row)
#define G2L 4096     // [128][32] g2 lo, same swizzle
#define G2T 8192     // [32][136] g2^T * es[k], rows PERMUTED, hi only
#define H2T 12544    // [4][136] h2^T * es[k], row 3 zeros
#define SM_U16 13088 // 26176 B + 3088 smf = 29264 B -> 4 blocks/CU (wave cap)

#define RPERM(C) ((((C) >> 2) & 1) * 16 + (((C) >> 3) << 2) + ((C) & 3))
#define KEY(R) ((((R) & 3) ^ (((R) >> 3) & 3)) << 3)

#define CC_(a,b) a##b
#define CC(a,b) CC_(a,b)

// declare 8 named HL splits; IDX must be a function-like macro
#define LD8(NM, IDX) \
    HL CC(NM,0) = splitbf(IDX(0)), CC(NM,1) = splitbf(IDX(1)), \
       CC(NM,2) = splitbf(IDX(2)), CC(NM,3) = splitbf(IDX(3)), \
       CC(NM,4) = splitbf(IDX(4)), CC(NM,5) = splitbf(IDX(5)), \
       CC(NM,6) = splitbf(IDX(6)), CC(NM,7) = splitbf(IDX(7));
#define HI8(NM) mkv8(pk2(CC(NM,0).hi, CC(NM,1).hi), pk2(CC(NM,2).hi, CC(NM,3).hi), \
                     pk2(CC(NM,4).hi, CC(NM,5).hi), pk2(CC(NM,6).hi, CC(NM,7).hi))
#define LO8(NM) mkv8(pk2(CC(NM,0).lo, CC(NM,1).lo), pk2(CC(NM,2).lo, CC(NM,3).lo), \
                     pk2(CC(NM,4).lo, CC(NM,5).lo), pk2(CC(NM,6).lo, CC(NM,7).lo))

#define WKI(J) wqk[(mt * 16 + n16) * 256 + (quad * 8 + (J)) * 8 + 4 + h]
#define WVI(J) wv[(mt * 16 + n16) * 128 + (quad * 8 + (J)) * 4 + h]
#define WQI(J) wqk[(nt * 16 + n16) * 256 + (quad * 8 + (J)) * 8 + h]
#define WHI(J) wh[((quad * 8 + (J)) * 4 + h) * 32 + nt * 16 + n16]

// ======= pre-kernel: fold weights once into ws (8 blocks x 64 thr) =========
__global__ __launch_bounds__(64) void fold_kernel(
    const float* __restrict__ wqk, const float* __restrict__ wv,
    const float* __restrict__ wh, unsigned short* __restrict__ wsu)
{
    const int lane = threadIdx.x;              // 0..63
    const int quad = lane >> 4;
    const int n16  = lane & 15;
    const int h    = blockIdx.x & 3;           // head
    const int mt   = blockIdx.x >> 2;          // row-block

    LD8(ak, WKI)                               // Wk[c][d] splits
    LD8(av, WVI)                               // Wv[c][g] splits
    const v8bf akh = HI8(ak), akl = LO8(ak);
    const v8bf avh = HI8(av), avl = LO8(av);
    FENCE();
    #pragma unroll 1
    for (int nt = 0; nt < 2; nt++) {
        LD8(bq, WQI)                           // Wq[c'][d] splits
        LD8(bw, WHI)                           // Wh[g][o] splits
        const v8bf bqh = HI8(bq), bql = LO8(bq);
        const v8bf bhh = HI8(bw), bhl = LO8(bw);
        FENCE();
        const v4f z = {0.f, 0.f, 0.f, 0.f};
        // c1[r] = M[nt*16+n16][x], x = mt*16+quad*4+r  (M = Wq Wk^T)
        v4f c1 = MF(akh, bqh, MF(akl, bqh, MF(akh, bql, z)));
        #pragma unroll
        for (int r = 0; r < 4; r++) {
            HL s1 = splitbf(c1[r]);
            int x    = mt * 16 + quad * 4 + r;
            int rowp = RPERM(x);
            int addr = h * 1024 + rowp * 32 + ((nt * 16 + n16) ^ KEY(rowp));
            wsu[NQHo + addr] = s1.hi; wsu[NQLo + addr] = s1.lo;
        }
        // c2[r] = W2fold[c = mt*16+quad*4+r][o = nt*16+n16]
        v4f c2 = MF(avh, bhh, MF(avl, bhh, MF(avh, bhl, z)));
        #pragma unroll
        for (int r = 0; r < 4; r++) {
            int o  = nt * 16 + n16;
            int cw = mt * 16 + quad * 4 + r;
            wsu[PQo + h * 1024 + o * 32 + (cw ^ KEY(o))] = fb(c2[r]);
        }
        FENCE();
    }
}

// ============================ main kernel ====================================
__global__ __launch_bounds__(512, 4) void repformer_kernel(
    const float* __restrict__ g2, const float* __restrict__ h2,
    const float* __restrict__ sw, const float* __restrict__ bh,
    const float* __restrict__ weq, const int* __restrict__ nmask,
    const unsigned short* __restrict__ wsu, float* __restrict__ out)
{
    __shared__ __align__(16) unsigned short sm[SM_U16];
    __shared__ __align__(16) float smf[772];   // h2s[512] | sws[128] | es[128] | weq[4]
    float* h2s = smf;
    float* sws = smf + 512;
    float* es  = smf + 640;
    float* wqs = smf + 768;

    const int t    = threadIdx.x;              // 0..511
    const int i    = blockIdx.x;
    const int lane = t & 63;
    const int w8   = t >> 6;                   // wave 0..7
    const int quad = lane >> 4;
    const int n16  = lane & 15;

    // ------- stage per-loc inputs (es folded inline into G2T/H2T) -------
    {
        const float4* src = (const float4*)(g2 + (size_t)i * 4096);
        #pragma unroll
        for (int j = 0; j < 2; j++) {
            int idx = j * 512 + t;
            float4 v = src[idx];
            HL a0 = splitbf(v.x), a1 = splitbf(v.y), a2 = splitbf(v.z), a3 = splitbf(v.w);
            int k = idx >> 3, c0 = (idx & 7) * 4;
            int swz = k * 32 + (c0 ^ KEY(k));
            *(u32x2*)(sm + G2H + swz) = (u32x2){pk2(a0.hi, a1.hi), pk2(a2.hi, a3.hi)};
            *(u32x2*)(sm + G2L + swz) = (u32x2){pk2(a0.lo, a1.lo), pk2(a2.lo, a3.lo)};
            float ek = (nmask[i * 128 + k] != 0) ? sw[i * 128 + k] : 0.0f;
            sm[G2T + RPERM(c0 + 0) * 136 + k] = fb(b2f(a0.hi) * ek);
            sm[G2T + RPERM(c0 + 1) * 136 + k] = fb(b2f(a1.hi) * ek);
            sm[G2T + RPERM(c0 + 2) * 136 + k] = fb(b2f(a2.hi) * ek);
            sm[G2T + RPERM(c0 + 3) * 136 + k] = fb(b2f(a3.hi) * ek);
        }
    }
    if (t < 384) {
        float f = h2[(size_t)i * 384 + t];
        int k = t / 3, c = t - k * 3;
        h2s[k * 4 + c] = f;
        float ek = (nmask[i * 128 + k] != 0) ? sw[i * 128 + k] : 0.0f;
        unsigned short us = fb(f);
        sm[H2T + c * 136 + k] = fb(b2f(us) * ek);
    }
    if (t < 128) {
        sm[H2T + 3 * 136 + t] = 0;
        float s = sw[i * 128 + t];
        sws[t] = s;
        es[t]  = (nmask[i * 128 + t] != 0) ? s : 0.0f;
    }
    if (t < 4) wqs[t] = weq[t];
    __syncthreads();   // all LDS is READ-ONLY from here to the end

    const int hr = (n16 < 3) ? n16 : 3;
    float* outg = out;
    float* outh = out + 4194304;   // 1024*128*32
    const float bias0 = bh[n16];
    const float bias1 = bh[16 + n16];
    // swizzled col bases (per-lane constants):
    const int qo0 = (quad * 8) ^ KEY(n16);               // NQ/PQ tile0 (row n16)
    const int qo1 = (quad * 8) ^ KEY(16 + n16);          // NQ/PQ tile1 (row 16+n16)
    const int rowbase = ((n16 >> 2) << 3) + (n16 & 3);   // S^T A-row permutation
    const int qoK = (quad * 8) ^ KEY(rowbase);           // KSSTEP A-rows
    const unsigned short* g2t0 = sm + G2T + n16 * 136;
    const unsigned short* g2t1 = sm + G2T + (16 + n16) * 136;
    const unsigned short* h2tp = sm + H2T + hr * 136;

// one 32-kn chunk: 2 S^T tiles -> packed-f32 softmax -> P-frag -> 3 value MFMAs
#define KSSTEP(KS, HWA, HWB) { \
    const int rowA = (KS) * 32 + rowbase; \
    const v8bf ah0 = *(const v8bf*)(sm + G2H + rowA * 32 + qoK); \
    const v8bf al0 = *(const v8bf*)(sm + G2L + rowA * 32 + qoK); \
    const v8bf ah1 = *(const v8bf*)(sm + G2H + (rowA + 4) * 32 + qoK); \
    const v8bf al1 = *(const v8bf*)(sm + G2L + (rowA + 4) * 32 + qoK); \
    const v4f st0 = MF(ah0, ql, MF(al0, qh, MF(ah0, qh, vz))); \
    const v4f st1 = MF(ah1, ql, MF(al1, qh, MF(ah1, qh, vz))); \
    const v4f swkA = *(const v4f*)(sws + (KS) * 32 + quad * 8); \
    const v4f swkB = *(const v4f*)(sws + (KS) * 32 + quad * 8 + 4); \
    const f2 l01 = FMA2(FMA2(mkf2(st0[0], st0[1]), mkf2((HWA)[0], (HWA)[1]), sq2v), \
                        mkf2(swkA[0], swkA[1]), mshv); \
    const f2 l23 = FMA2(FMA2(mkf2(st0[2], st0[3]), mkf2((HWA)[2], (HWA)[3]), sq2v), \
                        mkf2(swkA[2], swkA[3]), mshv); \
    const f2 l45 = FMA2(FMA2(mkf2(st1[0], st1[1]), mkf2((HWB)[0], (HWB)[1]), sq2v), \
                        mkf2(swkB[0], swkB[1]), mshv); \
    const f2 l67 = FMA2(FMA2(mkf2(st1[2], st1[3]), mkf2((HWB)[2], (HWB)[3]), sq2v), \
                        mkf2(swkB[2], swkB[3]), mshv); \
    const f2 p01 = mkf2(EXP2(l01[0]), EXP2(l01[1])); \
    const f2 p23 = mkf2(EXP2(l23[0]), EXP2(l23[1])); \
    const f2 p45 = mkf2(EXP2(l45[0]), EXP2(l45[1])); \
    const f2 p67 = mkf2(EXP2(l67[0]), EXP2(l67[1])); \
    sum2 += (p01 + p23) + (p45 + p67); \
    const f2 h01 = p01 * mkf2((HWA)[0], (HWA)[1]); \
    const f2 h23 = p23 * mkf2((HWA)[2], (HWA)[3]); \
    const f2 h45 = p45 * mkf2((HWB)[0], (HWB)[1]); \
    const f2 h67 = p67 * mkf2((HWB)[2], (HWB)[3]); \
    const v8bf pv = mkv8(cvt2(h01[0], h01[1]), cvt2(h23[0], h23[1]), \
                         cvt2(h45[0], h45[1]), cvt2(h67[0], h67[1])); \
    T0  = MF(*(const v8bf*)(g2t0 + (KS) * 32 + quad * 8), pv, T0); \
    T1  = MF(*(const v8bf*)(g2t1 + (KS) * 32 + quad * 8), pv, T1); \
    ohl = MF(*(const v8bf*)(h2tp + (KS) * 32 + quad * 8), pv, ohl); \
}

    // ============ ONE strip per wave (8 waves), heads INNER (rolled) ========
    {
        const int s = w8;
        const int q = s * 16 + n16;                      // this lane's q-row
        const int qoq = (quad * 8) ^ KEY(q);
        const v8bf gfh = *(const v8bf*)(sm + G2H + q * 32 + qoq);
        const v8bf gfl = *(const v8bf*)(sm + G2L + q * 32 + qoq);
        const float swq    = sws[q];
        const float mq     = (es[q] != 0.0f) ? 1.0f : 0.0f;
        const float swq20E = swq * 28.853900817779268f;  // 20*swq*log2e
        const f2 sq2v = mkf2(swq20E, swq20E);
        const f2 mshv = mkf2(MSH, MSH);
        const float kq     = 0.17677669529663687f * 1.4426950408889634f * swq;
        const float hq0 = h2s[q * 4 + 0] * kq;
        const float hq1 = h2s[q * 4 + 1] * kq;
        const float hq2 = h2s[q * 4 + 2] * kq;
        // htcwE = ht*swq/sqrt(32)*log2e, 8 named v4f (no arrays)
#define HW4(T8) (v4f){ hwe(h2s, ((T8) >> 1) * 32 + quad * 8 + ((T8) & 1) * 4 + 0, hq0, hq1, hq2), \
                       hwe(h2s, ((T8) >> 1) * 32 + quad * 8 + ((T8) & 1) * 4 + 1, hq0, hq1, hq2), \
                       hwe(h2s, ((T8) >> 1) * 32 + quad * 8 + ((T8) & 1) * 4 + 2, hq0, hq1, hq2), \
                       hwe(h2s, ((T8) >> 1) * 32 + quad * 8 + ((T8) & 1) * 4 + 3, hq0, hq1, hq2) }
        const v4f hw0 = HW4(0), hw1 = HW4(1), hw2 = HW4(2), hw3 = HW4(3);
        const v4f hw4 = HW4(4), hw5 = HW4(5), hw6 = HW4(6), hw7 = HW4(7);
        v4f og0 = {0.f, 0.f, 0.f, 0.f}, og1 = og0, ohacc = og0;
        FENCE();

        #pragma unroll 1
        for (int h0 = 0; h0 < 4; h0++) {
            const int hd = (h0 + w8) & 3;                // per-wave head rotation
            const v4f vz = {0.f, 0.f, 0.f, 0.f};
            // ---- q2^T: 2 C-tiles; NQ frags from GLOBAL ws (L2-hot) ----
            const unsigned short* nqh = wsu + NQHo + hd * 1024;
            const unsigned short* nql = wsu + NQLo + hd * 1024;
            const v8bf nh0 = *(const v8bf*)(nqh + n16 * 32 + qo0);
            const v8bf nl0 = *(const v8bf*)(nql + n16 * 32 + qo0);
            const v8bf nh1 = *(const v8bf*)(nqh + (16 + n16) * 32 + qo1);
            const v8bf nl1 = *(const v8bf*)(nql + (16 + n16) * 32 + qo1);
            // ---- PQ frags hoisted here: L2 latency hides under the softmax
            const unsigned short* wp = wsu + PQo + hd * 1024;
            const v8bf w0f = *(const v8bf*)(wp + n16 * 32 + qo0);
            const v8bf w1f = *(const v8bf*)(wp + (16 + n16) * 32 + qo1);
            v4f c0t = MF(nh0, gfl, MF(nl0, gfh, MF(nh0, gfh, vz)));
            v4f c1t = MF(nh1, gfl, MF(nl1, gfh, MF(nh1, gfh, vz)));
            unsigned qh0, qh1, qh2, qh3, ql0, ql1, ql2, ql3;
            sp2(c0t[0], c0t[1], qh0, ql0);
            sp2(c0t[2], c0t[3], qh1, ql1);
            sp2(c1t[0], c1t[1], qh2, ql2);
            sp2(c1t[2], c1t[3], qh3, ql3);
            const v8bf qh = mkv8(qh0, qh1, qh2, qh3);
            const v8bf ql = mkv8(ql0, ql1, ql2, ql3);
            // ---- 4 x 32-kn chunks (no mid fence; end fence pins backedge)
            v4f T0 = vz, T1 = vz, ohl = vz;
            f2 sum2 = mkf2(0.f, 0.f);
            KSSTEP(0, hw0, hw1)
            KSSTEP(1, hw2, hw3)
            KSSTEP(2, hw4, hw5)
            KSSTEP(3, hw6, hw7)
            float sum = sum2[0] + sum2[1];
            sum += __shfl_xor(sum, 16, 64);
            sum += __shfl_xor(sum, 32, 64);
            // mq * sqrt(32)/sqrt(3) * ln2 / denom  (ln2 un-does log2e in htcwE)
            const float scale = mq * 2.2638092f * __builtin_amdgcn_rcpf(sum);
            const f2 sc2 = mkf2(scale, scale);
            const f2 t01 = sc2 * mkf2(T0[0], T0[1]);
            const f2 t23 = sc2 * mkf2(T0[2], T0[3]);
            const f2 t45 = sc2 * mkf2(T1[0], T1[1]);
            const f2 t67 = sc2 * mkf2(T1[2], T1[3]);
            const v8bf ta = mkv8(cvt2(t01[0], t01[1]), cvt2(t23[0], t23[1]),
                                 cvt2(t45[0], t45[1]), cvt2(t67[0], t67[1]));
            og0 = MF(ta, w0f, og0);
            og1 = MF(ta, w1f, og1);
            const float ws = wqs[hd] * scale;
            ohacc[0] = fmaf(ws, ohl[0], ohacc[0]);
            ohacc[1] = fmaf(ws, ohl[1], ohacc[1]);
            ohacc[2] = fmaf(ws, ohl[2], ohacc[2]);
            ohacc[3] = fmaf(ws, ohl[3], ohacc[3]);
            FENCE();
        }

        // ---- strip epilogue (f32 out): og rows = q (quad*4+r), cols = o ----
        const int qg = i * 128 + s * 16;
        #pragma unroll
        for (int r = 0; r < 4; r++) {
            outg[(size_t)(qg + quad * 4 + r) * 32 + n16]      = og0[r] + bias0;
            outg[(size_t)(qg + quad * 4 + r) * 32 + 16 + n16] = og1[r] + bias1;
        }
        if (quad == 0) {
            #pragma unroll
            for (int r = 0; r < 3; r++)
                outh[(size_t)(qg + n16) * 3 + r] = ohacc[r];
        }
    }
}

extern "C" void kernel_launch(void* const* d_in, const int* in_sizes, int n_in,
                              void* d_out, int out_size, void* d_ws, size_t ws_size,
                              hipStream_t stream) {
    const float* g2  = (const float*)d_in[0];
    const float* h2  = (const float*)d_in[1];
    const float* sw  = (const float*)d_in[2];
    const float* wqk = (const float*)d_in[3];
    const float* wv  = (const float*)d_in[4];
    const float* wh  = (const float*)d_in[5];
    const float* bh  = (const float*)d_in[6];
    const float* weq = (const float*)d_in[7];
    const int*   nm  = (const int*)d_in[8];
    unsigned short* wsu = (unsigned short*)d_ws;       // needs 24576 B
    int nloc = in_sizes[0] / (128 * 32);   // 1024
    fold_kernel<<<8, 64, 0, stream>>>(wqk, wv, wh, wsu);
    repformer_kernel<<<nloc, 512, 0, stream>>>(g2, h2, sw, bh, weq, nm, wsu, (float*)d_out);
}

// Round 16
// 119.534 us; speedup vs baseline: 2.4411x; 1.0053x over previous
//
#include <hip/hip_runtime.h>

// RepformerLayer attention: nf=1, nloc=1024, nnei=128, ng2=nd=32, nh=4. f32 I/O.
// Transposed dataflow, K32-only (r2 math): q2^T C-layout feeds S^T MFMAs via
// PERMUTED NQ rows; permuted G2T rows make T^T C-tiles concat into the og
// A-frag; S^T A-rows read permuted so lane-local P rows land in value-MFMA
// B-frag k-slots. Lane holds a full softmax ROW (2-shuffle denom); P/T never
// touch LDS. hd loop ROLLED + ONE end-of-head FENCE (r5/r13: load-bearing —
// without it LLVM pipelines across the backedge and spills at the 64-VGPR
// cap). Native cvt_pk (r6); packed-f32 softmax + head rotation (r11); PQ
// loads hoisted (r12); 512-thr blocks, one strip/wave, 4 blocks/CU = 8
// waves/SIMD (r9); fold pre-kernel 8x64 (r14).
// r15 LESSON (reverted): scale is per-q and T's C-layout has the lane's own
// q (n16) — normalize BEFORE the og-MFMA. Post-MFMA scaling hits C rows
// q=quad*4+r with the scale of q=n16 (cross-lane mismatch) -> garbage.
// This is r14 verbatim: the session-best configuration (120.2 us wall).

typedef __bf16 v8bf __attribute__((ext_vector_type(8)));
typedef float  v4f  __attribute__((ext_vector_type(4)));
typedef float  f2   __attribute__((ext_vector_type(2)));
typedef unsigned u32x2 __attribute__((ext_vector_type(2)));
typedef unsigned u32x4 __attribute__((ext_vector_type(4)));

__device__ __forceinline__ float b2f(unsigned short b) {
    union { unsigned u; float f; } x; x.u = ((unsigned)b) << 16; return x.f;
}
__device__ __forceinline__ unsigned short fb(float f) {      // RNE f32->bf16
    return __builtin_bit_cast(unsigned short, (__bf16)f);
}
struct HL { unsigned short hi, lo; };
__device__ __forceinline__ HL splitbf(float f) {
    HL r; r.hi = fb(f); r.lo = fb(f - b2f(r.hi)); return r;
}
__device__ __forceinline__ unsigned pk2(unsigned short lo, unsigned short hi) {
    return ((unsigned)hi << 16) | (unsigned)lo;
}
__device__ __forceinline__ unsigned cvt2(float a, float b) { // lo=a hi=b
    return pk2(fb(a), fb(b));
}
__device__ __forceinline__ void sp2(float a, float b, unsigned& hi, unsigned& lo) {
    __bf16 ah = (__bf16)a, bh = (__bf16)b;
    hi = pk2(__builtin_bit_cast(unsigned short, ah), __builtin_bit_cast(unsigned short, bh));
    lo = cvt2(a - (float)ah, b - (float)bh);
}
__device__ __forceinline__ v8bf mkv8(unsigned a, unsigned b, unsigned c, unsigned d) {
    u32x4 x = {a, b, c, d};
    return __builtin_bit_cast(v8bf, x);
}
__device__ __forceinline__ f2 mkf2(float a, float b) {
    f2 r; r[0] = a; r[1] = b; return r;
}
__device__ __forceinline__ float hwe(const float* h2s, int kn,
                                     float hq0, float hq1, float hq2) {
    const v4f hk = *(const v4f*)(h2s + kn * 4);
    return fmaf(hq2, hk[2], fmaf(hq1, hk[1], hq0 * hk[0]));
}

#define MF(a,b,c) __builtin_amdgcn_mfma_f32_16x16x32_bf16((a),(b),(c),0,0,0)
#define FENCE() asm volatile("" ::: "memory")
#define FMA2(a,b,c) __builtin_elementwise_fma((a),(b),(c))

#if __has_builtin(__builtin_amdgcn_exp2f)
#define EXP2(x) __builtin_amdgcn_exp2f(x)
#else
#define EXP2(x) __expf((x) * 0.6931471805599453f)
#endif

#define MSH (-28.853900817779268f)

// ws offsets (u16 units): NQH 0 | NQL 4096 | PQ 8192  (24576 B total)
#define NQHo 0
#define NQLo 4096
#define PQo  8192

// LDS offsets (u16 units), main kernel
#define G2H 0        // [128][32] g2 hi, col ^= KEY(row)
#define G2L 4096     // [128][32] g2 lo, same swizzle
#define G2T 8192     // [32][136] g2^T * es[k], rows PERMUTED, hi only
#define H2T 12544    // [4][136] h2^T * es[k], row 3 zeros
#define SM_U16 13088 // 26176 B + 3088 smf = 29264 B -> 4 blocks/CU (wave cap)

#define RPERM(C) ((((C) >> 2) & 1) * 16 + (((C) >> 3) << 2) + ((C) & 3))
#define KEY(R) ((((R) & 3) ^ (((R) >> 3) & 3)) << 3)

#define CC_(a,b) a##b
#define CC(a,b) CC_(a,b)

// declare 8 named HL splits; IDX must be a function-like macro
#define LD8(NM, IDX) \
    HL CC(NM,0) = splitbf(IDX(0)), CC(NM,1) = splitbf(IDX(1)), \
       CC(NM,2) = splitbf(IDX(2)), CC(NM,3) = splitbf(IDX(3)), \
       CC(NM,4) = splitbf(IDX(4)), CC(NM,5) = splitbf(IDX(5)), \
       CC(NM,6) = splitbf(IDX(6)), CC(NM,7) = splitbf(IDX(7));
#define HI8(NM) mkv8(pk2(CC(NM,0).hi, CC(NM,1).hi), pk2(CC(NM,2).hi, CC(NM,3).hi), \
                     pk2(CC(NM,4).hi, CC(NM,5).hi), pk2(CC(NM,6).hi, CC(NM,7).hi))
#define LO8(NM) mkv8(pk2(CC(NM,0).lo, CC(NM,1).lo), pk2(CC(NM,2).lo, CC(NM,3).lo), \
                     pk2(CC(NM,4).lo, CC(NM,5).lo), pk2(CC(NM,6).lo, CC(NM,7).lo))

#define WKI(J) wqk[(mt * 16 + n16) * 256 + (quad * 8 + (J)) * 8 + 4 + h]
#define WVI(J) wv[(mt * 16 + n16) * 128 + (quad * 8 + (J)) * 4 + h]
#define WQI(J) wqk[(nt * 16 + n16) * 256 + (quad * 8 + (J)) * 8 + h]
#define WHI(J) wh[((quad * 8 + (J)) * 4 + h) * 32 + nt * 16 + n16]

// ======= pre-kernel: fold weights once into ws (8 blocks x 64 thr) =========
__global__ __launch_bounds__(64) void fold_kernel(
    const float* __restrict__ wqk, const float* __restrict__ wv,
    const float* __restrict__ wh, unsigned short* __restrict__ wsu)
{
    const int lane = threadIdx.x;              // 0..63
    const int quad = lane >> 4;
    const int n16  = lane & 15;
    const int h    = blockIdx.x & 3;           // head
    const int mt   = blockIdx.x >> 2;          // row-block

    LD8(ak, WKI)                               // Wk[c][d] splits
    LD8(av, WVI)                               // Wv[c][g] splits
    const v8bf akh = HI8(ak), akl = LO8(ak);
    const v8bf avh = HI8(av), avl = LO8(av);
    FENCE();
    #pragma unroll 1
    for (int nt = 0; nt < 2; nt++) {
        LD8(bq, WQI)                           // Wq[c'][d] splits
        LD8(bw, WHI)                           // Wh[g][o] splits
        const v8bf bqh = HI8(bq), bql = LO8(bq);
        const v8bf bhh = HI8(bw), bhl = LO8(bw);
        FENCE();
        const v4f z = {0.f, 0.f, 0.f, 0.f};
        // c1[r] = M[nt*16+n16][x], x = mt*16+quad*4+r  (M = Wq Wk^T)
        v4f c1 = MF(akh, bqh, MF(akl, bqh, MF(akh, bql, z)));
        #pragma unroll
        for (int r = 0; r < 4; r++) {
            HL s1 = splitbf(c1[r]);
            int x    = mt * 16 + quad * 4 + r;
            int rowp = RPERM(x);
            int addr = h * 1024 + rowp * 32 + ((nt * 16 + n16) ^ KEY(rowp));
            wsu[NQHo + addr] = s1.hi; wsu[NQLo + addr] = s1.lo;
        }
        // c2[r] = W2fold[c = mt*16+quad*4+r][o = nt*16+n16]
        v4f c2 = MF(avh, bhh, MF(avl, bhh, MF(avh, bhl, z)));
        #pragma unroll
        for (int r = 0; r < 4; r++) {
            int o  = nt * 16 + n16;
            int cw = mt * 16 + quad * 4 + r;
            wsu[PQo + h * 1024 + o * 32 + (cw ^ KEY(o))] = fb(c2[r]);
        }
        FENCE();
    }
}

// ============================ main kernel ====================================
__global__ __launch_bounds__(512, 4) void repformer_kernel(
    const float* __restrict__ g2, const float* __restrict__ h2,
    const float* __restrict__ sw, const float* __restrict__ bh,
    const float* __restrict__ weq, const int* __restrict__ nmask,
    const unsigned short* __restrict__ wsu, float* __restrict__ out)
{
    __shared__ __align__(16) unsigned short sm[SM_U16];
    __shared__ __align__(16) float smf[772];   // h2s[512] | sws[128] | es[128] | weq[4]
    float* h2s = smf;
    float* sws = smf + 512;
    float* es  = smf + 640;
    float* wqs = smf + 768;

    const int t    = threadIdx.x;              // 0..511
    const int i    = blockIdx.x;
    const int lane = t & 63;
    const int w8   = t >> 6;                   // wave 0..7
    const int quad = lane >> 4;
    const int n16  = lane & 15;

    // ------- stage per-loc inputs (es folded inline into G2T/H2T) -------
    {
        const float4* src = (const float4*)(g2 + (size_t)i * 4096);
        #pragma unroll
        for (int j = 0; j < 2; j++) {
            int idx = j * 512 + t;
            float4 v = src[idx];
            HL a0 = splitbf(v.x), a1 = splitbf(v.y), a2 = splitbf(v.z), a3 = splitbf(v.w);
            int k = idx >> 3, c0 = (idx & 7) * 4;
            int swz = k * 32 + (c0 ^ KEY(k));
            *(u32x2*)(sm + G2H + swz) = (u32x2){pk2(a0.hi, a1.hi), pk2(a2.hi, a3.hi)};
            *(u32x2*)(sm + G2L + swz) = (u32x2){pk2(a0.lo, a1.lo), pk2(a2.lo, a3.lo)};
            float ek = (nmask[i * 128 + k] != 0) ? sw[i * 128 + k] : 0.0f;
            sm[G2T + RPERM(c0 + 0) * 136 + k] = fb(b2f(a0.hi) * ek);
            sm[G2T + RPERM(c0 + 1) * 136 + k] = fb(b2f(a1.hi) * ek);
            sm[G2T + RPERM(c0 + 2) * 136 + k] = fb(b2f(a2.hi) * ek);
            sm[G2T + RPERM(c0 + 3) * 136 + k] = fb(b2f(a3.hi) * ek);
        }
    }
    if (t < 384) {
        float f = h2[(size_t)i * 384 + t];
        int k = t / 3, c = t - k * 3;
        h2s[k * 4 + c] = f;
        float ek = (nmask[i * 128 + k] != 0) ? sw[i * 128 + k] : 0.0f;
        unsigned short us = fb(f);
        sm[H2T + c * 136 + k] = fb(b2f(us) * ek);
    }
    if (t < 128) {
        sm[H2T + 3 * 136 + t] = 0;
        float s = sw[i * 128 + t];
        sws[t] = s;
        es[t]  = (nmask[i * 128 + t] != 0) ? s : 0.0f;
    }
    if (t < 4) wqs[t] = weq[t];
    __syncthreads();   // all LDS is READ-ONLY from here to the end

    const int hr = (n16 < 3) ? n16 : 3;
    float* outg = out;
    float* outh = out + 4194304;   // 1024*128*32
    const float bias0 = bh[n16];
    const float bias1 = bh[16 + n16];
    // swizzled col bases (per-lane constants):
    const int qo0 = (quad * 8) ^ KEY(n16);               // NQ/PQ tile0 (row n16)
    const int qo1 = (quad * 8) ^ KEY(16 + n16);          // NQ/PQ tile1 (row 16+n16)
    const int rowbase = ((n16 >> 2) << 3) + (n16 & 3);   // S^T A-row permutation
    const int qoK = (quad * 8) ^ KEY(rowbase);           // KSSTEP A-rows
    const unsigned short* g2t0 = sm + G2T + n16 * 136;
    const unsigned short* g2t1 = sm + G2T + (16 + n16) * 136;
    const unsigned short* h2tp = sm + H2T + hr * 136;

// one 32-kn chunk: 2 S^T tiles -> packed-f32 softmax -> P-frag -> 3 value MFMAs
#define KSSTEP(KS, HWA, HWB) { \
    const int rowA = (KS) * 32 + rowbase; \
    const v8bf ah0 = *(const v8bf*)(sm + G2H + rowA * 32 + qoK); \
    const v8bf al0 = *(const v8bf*)(sm + G2L + rowA * 32 + qoK); \
    const v8bf ah1 = *(const v8bf*)(sm + G2H + (rowA + 4) * 32 + qoK); \
    const v8bf al1 = *(const v8bf*)(sm + G2L + (rowA + 4) * 32 + qoK); \
    const v4f st0 = MF(ah0, ql, MF(al0, qh, MF(ah0, qh, vz))); \
    const v4f st1 = MF(ah1, ql, MF(al1, qh, MF(ah1, qh, vz))); \
    const v4f swkA = *(const v4f*)(sws + (KS) * 32 + quad * 8); \
    const v4f swkB = *(const v4f*)(sws + (KS) * 32 + quad * 8 + 4); \
    const f2 l01 = FMA2(FMA2(mkf2(st0[0], st0[1]), mkf2((HWA)[0], (HWA)[1]), sq2v), \
                        mkf2(swkA[0], swkA[1]), mshv); \
    const f2 l23 = FMA2(FMA2(mkf2(st0[2], st0[3]), mkf2((HWA)[2], (HWA)[3]), sq2v), \
                        mkf2(swkA[2], swkA[3]), mshv); \
    const f2 l45 = FMA2(FMA2(mkf2(st1[0], st1[1]), mkf2((HWB)[0], (HWB)[1]), sq2v), \
                        mkf2(swkB[0], swkB[1]), mshv); \
    const f2 l67 = FMA2(FMA2(mkf2(st1[2], st1[3]), mkf2((HWB)[2], (HWB)[3]), sq2v), \
                        mkf2(swkB[2], swkB[3]), mshv); \
    const f2 p01 = mkf2(EXP2(l01[0]), EXP2(l01[1])); \
    const f2 p23 = mkf2(EXP2(l23[0]), EXP2(l23[1])); \
    const f2 p45 = mkf2(EXP2(l45[0]), EXP2(l45[1])); \
    const f2 p67 = mkf2(EXP2(l67[0]), EXP2(l67[1])); \
    sum2 += (p01 + p23) + (p45 + p67); \
    const f2 h01 = p01 * mkf2((HWA)[0], (HWA)[1]); \
    const f2 h23 = p23 * mkf2((HWA)[2], (HWA)[3]); \
    const f2 h45 = p45 * mkf2((HWB)[0], (HWB)[1]); \
    const f2 h67 = p67 * mkf2((HWB)[2], (HWB)[3]); \
    const v8bf pv = mkv8(cvt2(h01[0], h01[1]), cvt2(h23[0], h23[1]), \
                         cvt2(h45[0], h45[1]), cvt2(h67[0], h67[1])); \
    T0  = MF(*(const v8bf*)(g2t0 + (KS) * 32 + quad * 8), pv, T0); \
    T1  = MF(*(const v8bf*)(g2t1 + (KS) * 32 + quad * 8), pv, T1); \
    ohl = MF(*(const v8bf*)(h2tp + (KS) * 32 + quad * 8), pv, ohl); \
}

    // ============ ONE strip per wave (8 waves), heads INNER (rolled) ========
    {
        const int s = w8;
        const int q = s * 16 + n16;                      // this lane's q-row
        const int qoq = (quad * 8) ^ KEY(q);
        const v8bf gfh = *(const v8bf*)(sm + G2H + q * 32 + qoq);
        const v8bf gfl = *(const v8bf*)(sm + G2L + q * 32 + qoq);
        const float swq    = sws[q];
        const float mq     = (es[q] != 0.0f) ? 1.0f : 0.0f;
        const float swq20E = swq * 28.853900817779268f;  // 20*swq*log2e
        const f2 sq2v = mkf2(swq20E, swq20E);
        const f2 mshv = mkf2(MSH, MSH);
        const float kq     = 0.17677669529663687f * 1.4426950408889634f * swq;
        const float hq0 = h2s[q * 4 + 0] * kq;
        const float hq1 = h2s[q * 4 + 1] * kq;
        const float hq2 = h2s[q * 4 + 2] * kq;
        // htcwE = ht*swq/sqrt(32)*log2e, 8 named v4f (no arrays)
#define HW4(T8) (v4f){ hwe(h2s, ((T8) >> 1) * 32 + quad * 8 + ((T8) & 1) * 4 + 0, hq0, hq1, hq2), \
                       hwe(h2s, ((T8) >> 1) * 32 + quad * 8 + ((T8) & 1) * 4 + 1, hq0, hq1, hq2), \
                       hwe(h2s, ((T8) >> 1) * 32 + quad * 8 + ((T8) & 1) * 4 + 2, hq0, hq1, hq2), \
                       hwe(h2s, ((T8) >> 1) * 32 + quad * 8 + ((T8) & 1) * 4 + 3, hq0, hq1, hq2) }
        const v4f hw0 = HW4(0), hw1 = HW4(1), hw2 = HW4(2), hw3 = HW4(3);
        const v4f hw4 = HW4(4), hw5 = HW4(5), hw6 = HW4(6), hw7 = HW4(7);
        v4f og0 = {0.f, 0.f, 0.f, 0.f}, og1 = og0, ohacc = og0;
        FENCE();

        #pragma unroll 1
        for (int h0 = 0; h0 < 4; h0++) {
            const int hd = (h0 + w8) & 3;                // per-wave head rotation
            const v4f vz = {0.f, 0.f, 0.f, 0.f};
            // ---- q2^T: 2 C-tiles; NQ frags from GLOBAL ws (L2-hot) ----
            const unsigned short* nqh = wsu + NQHo + hd * 1024;
            const unsigned short* nql = wsu + NQLo + hd * 1024;
            const v8bf nh0 = *(const v8bf*)(nqh + n16 * 32 + qo0);
            const v8bf nl0 = *(const v8bf*)(nql + n16 * 32 + qo0);
            const v8bf nh1 = *(const v8bf*)(nqh + (16 + n16) * 32 + qo1);
            const v8bf nl1 = *(const v8bf*)(nql + (16 + n16) * 32 + qo1);
            // ---- PQ frags hoisted here: L2 latency hides under the softmax
            const unsigned short* wp = wsu + PQo + hd * 1024;
            const v8bf w0f = *(const v8bf*)(wp + n16 * 32 + qo0);
            const v8bf w1f = *(const v8bf*)(wp + (16 + n16) * 32 + qo1);
            v4f c0t = MF(nh0, gfl, MF(nl0, gfh, MF(nh0, gfh, vz)));
            v4f c1t = MF(nh1, gfl, MF(nl1, gfh, MF(nh1, gfh, vz)));
            unsigned qh0, qh1, qh2, qh3, ql0, ql1, ql2, ql3;
            sp2(c0t[0], c0t[1], qh0, ql0);
            sp2(c0t[2], c0t[3], qh1, ql1);
            sp2(c1t[0], c1t[1], qh2, ql2);
            sp2(c1t[2], c1t[3], qh3, ql3);
            const v8bf qh = mkv8(qh0, qh1, qh2, qh3);
            const v8bf ql = mkv8(ql0, ql1, ql2, ql3);
            // ---- 4 x 32-kn chunks (no mid fence; end fence pins backedge)
            v4f T0 = vz, T1 = vz, ohl = vz;
            f2 sum2 = mkf2(0.f, 0.f);
            KSSTEP(0, hw0, hw1)
            KSSTEP(1, hw2, hw3)
            KSSTEP(2, hw4, hw5)
            KSSTEP(3, hw6, hw7)
            float sum = sum2[0] + sum2[1];
            sum += __shfl_xor(sum, 16, 64);
            sum += __shfl_xor(sum, 32, 64);
            // mq * sqrt(32)/sqrt(3) * ln2 / denom  (ln2 un-does log2e in htcwE)
            const float scale = mq * 2.2638092f * __builtin_amdgcn_rcpf(sum);
            const f2 sc2 = mkf2(scale, scale);
            const f2 t01 = sc2 * mkf2(T0[0], T0[1]);
            const f2 t23 = sc2 * mkf2(T0[2], T0[3]);
            const f2 t45 = sc2 * mkf2(T1[0], T1[1]);
            const f2 t67 = sc2 * mkf2(T1[2], T1[3]);
            const v8bf ta = mkv8(cvt2(t01[0], t01[1]), cvt2(t23[0], t23[1]),
                                 cvt2(t45[0], t45[1]), cvt2(t67[0], t67[1]));
            og0 = MF(ta, w0f, og0);
            og1 = MF(ta, w1f, og1);
            const float ws = wqs[hd] * scale;
            ohacc[0] = fmaf(ws, ohl[0], ohacc[0]);
            ohacc[1] = fmaf(ws, ohl[1], ohacc[1]);
            ohacc[2] = fmaf(ws, ohl[2], ohacc[2]);
            ohacc[3] = fmaf(ws, ohl[3], ohacc[3]);
            FENCE();
        }

        // ---- strip epilogue (f32 out): og rows = q (quad*4+r), cols = o ----
        const int qg = i * 128 + s * 16;
        #pragma unroll
        for (int r = 0; r < 4; r++) {
            outg[(size_t)(qg + quad * 4 + r) * 32 + n16]      = og0[r] + bias0;
            outg[(size_t)(qg + quad * 4 + r) * 32 + 16 + n16] = og1[r] + bias1;
        }
        if (quad == 0) {
            #pragma unroll
            for (int r = 0; r < 3; r++)
                outh[(size_t)(qg + n16) * 3 + r] = ohacc[r];
        }
    }
}

extern "C" void kernel_launch(void* const* d_in, const int* in_sizes, int n_in,
                              void* d_out, int out_size, void* d_ws, size_t ws_size,
                              hipStream_t stream) {
    const float* g2  = (const float*)d_in[0];
    const float* h2  = (const float*)d_in[1];
    const float* sw  = (const float*)d_in[2];
    const float* wqk = (const float*)d_in[3];
    const float* wv  = (const float*)d_in[4];
    const float* wh  = (const float*)d_in[5];
    const float* bh  = (const float*)d_in[6];
    const float* weq = (const float*)d_in[7];
    const int*   nm  = (const int*)d_in[8];
    unsigned short* wsu = (unsigned short*)d_ws;       // needs 24576 B
    int nloc = in_sizes[0] / (128 * 32);   // 1024
    fold_kernel<<<8, 64, 0, stream>>>(wqk, wv, wh, wsu);
    repformer_kernel<<<nloc, 512, 0, stream>>>(g2, h2, sw, bh, weq, nm, wsu, (float*)d_out);
}